// Round 1
// baseline (567.685 us; speedup 1.0000x reference)
//
#include <hip/hip_runtime.h>
#include <cstdint>

// ---------- types ----------
typedef __bf16 bf16x8 __attribute__((ext_vector_type(8)));
typedef float  f32x4  __attribute__((ext_vector_type(4)));

// Problem constants
// BATCH=8, N_SEQS=4, SEQ_LEN=2048, D=512 -> 32 seqs, M = 65536 rows
#define SEQS   32
#define SLEN   2048
#define DIM    512
#define MROWS  65536

static __device__ __forceinline__ void load_lds16(const void* g, void* l) {
  // CK-style generic->AS cast via uintptr_t (amd_direct_load.hpp pattern)
  __builtin_amdgcn_global_load_lds(
      (const __attribute__((address_space(1))) void*)(uintptr_t)g,
      (__attribute__((address_space(3))) void*)(uintptr_t)l,
      16, 0, 0);
}

static __device__ __forceinline__ unsigned short bfbits(float f) {
  __bf16 h = (__bf16)f;
  unsigned short u;
  __builtin_memcpy(&u, &h, 2);
  return u;
}

// ---------- shared BT-GEMM core ----------
// C[m,n] += sum_k A[m,k]*B[n,k];  A row-major [*,lda], B row-major [*,ldb].
// 128x128 tile, BK=32, 256 threads (4 waves 2x2), 16x16x32 bf16 MFMA.
static __device__ __forceinline__ void gemm_core(
    const __bf16* __restrict__ A, int lda, int arow0,
    const __bf16* __restrict__ B, int ldb, int brow0,
    int K, __bf16* Asm, __bf16* Bsm, f32x4 (&acc)[4][4])
{
  const int tid  = threadIdx.x;
  const int wave = tid >> 6;
  const int lane = tid & 63;
  const int wr = wave >> 1, wc = wave & 1;
  const int lr = lane & 15, kq = lane >> 4;

  for (int kt = 0; kt < K; kt += 32) {
#pragma unroll
    for (int q = 0; q < 2; ++q) {
      const int b = q * 4096 + tid * 16;   // byte index in 8192B tile
      const int r = b >> 6;                // 64B per row (32 bf16)
      const int c = (b & 63) >> 1;         // element col within row
      load_lds16(A + (size_t)(arow0 + r) * lda + (kt + c),
                 (char*)Asm + q * 4096 + wave * 1024);
      load_lds16(B + (size_t)(brow0 + r) * ldb + (kt + c),
                 (char*)Bsm + q * 4096 + wave * 1024);
    }
    __syncthreads();   // drains vmcnt -> staged data visible

    bf16x8 af[4], bfr[4];
#pragma unroll
    for (int i = 0; i < 4; ++i)
      af[i] = *reinterpret_cast<const bf16x8*>(Asm + (wr * 64 + i * 16 + lr) * 32 + kq * 8);
#pragma unroll
    for (int j = 0; j < 4; ++j)
      bfr[j] = *reinterpret_cast<const bf16x8*>(Bsm + (wc * 64 + j * 16 + lr) * 32 + kq * 8);

#pragma unroll
    for (int i = 0; i < 4; ++i)
#pragma unroll
      for (int j = 0; j < 4; ++j)
        acc[i][j] = __builtin_amdgcn_mfma_f32_16x16x32_bf16(af[i], bfr[j], acc[i][j], 0, 0, 0);
    __syncthreads();   // protect LDS before next stage
  }
}

// ---------- kernels ----------

// fp32 -> bf16 cast, 8 elems/thread
__global__ __launch_bounds__(256) void cast_kernel(
    const float* __restrict__ src, __bf16* __restrict__ dst, int n8)
{
  int i = blockIdx.x * blockDim.x + threadIdx.x;
  const int stride = gridDim.x * blockDim.x;
  for (; i < n8; i += stride) {
    const float4* p = reinterpret_cast<const float4*>(src + (size_t)i * 8);
    float4 a = p[0], b2 = p[1];
    float vals[8] = {a.x, a.y, a.z, a.w, b2.x, b2.y, b2.z, b2.w};
    uint32_t w[4];
#pragma unroll
    for (int t = 0; t < 4; ++t)
      w[t] = (uint32_t)bfbits(vals[2 * t]) | ((uint32_t)bfbits(vals[2 * t + 1]) << 16);
    uint4 o; o.x = w[0]; o.y = w[1]; o.z = w[2]; o.w = w[3];
    *reinterpret_cast<uint4*>(dst + (size_t)i * 8) = o;
  }
}

// QKV projection: grid (512, 4, 3). z=0 -> Q (phi), z=1 -> K^T (phi), z=2 -> V^T
__global__ __launch_bounds__(256) void qkv_kernel(
    const __bf16* __restrict__ xb,
    const __bf16* __restrict__ Wqb, const __bf16* __restrict__ Wkb,
    const __bf16* __restrict__ Wvb,
    __bf16* __restrict__ Q, __bf16* __restrict__ KT, __bf16* __restrict__ VT)
{
  __shared__ __align__(16) __bf16 Asm[128 * 32];
  __shared__ __align__(16) __bf16 Bsm[128 * 32];
  const int brow = blockIdx.x, bcol = blockIdx.y, z = blockIdx.z;
  const __bf16* W = (z == 0) ? Wqb : (z == 1) ? Wkb : Wvb;
  f32x4 acc[4][4] = {};
  gemm_core(xb, DIM, brow * 128, W, DIM, bcol * 128, DIM, Asm, Bsm, acc);

  const int tid = threadIdx.x, wave = tid >> 6, lane = tid & 63;
  const int wr = wave >> 1, wc = wave & 1, lr = lane & 15, kq = lane >> 4;
  const int m0 = brow * 128 + wr * 64 + kq * 4;
  const int n0 = bcol * 128 + wc * 64 + lr;

  if (z == 0) {
#pragma unroll
    for (int i = 0; i < 4; ++i)
#pragma unroll
      for (int j = 0; j < 4; ++j) {
        const int n = n0 + j * 16;
#pragma unroll
        for (int r = 0; r < 4; ++r) {
          const int m = m0 + i * 16 + r;
          float v = acc[i][j][r];
          v = (v > 0.f) ? (v + 1.f) : __expf(v);   // elu(v)+1
          Q[(size_t)m * DIM + n] = (__bf16)v;
        }
      }
  } else {
    __bf16* T = (z == 1) ? KT : VT;
#pragma unroll
    for (int i = 0; i < 4; ++i) {
      const int mb  = m0 + i * 16;
      const int seq = mb >> 11;          // 2048 rows per seq
      const int s0  = mb & 2047;         // 4 consecutive s per lane
#pragma unroll
      for (int j = 0; j < 4; ++j) {
        const int d = n0 + j * 16;
        unsigned short h[4];
#pragma unroll
        for (int r = 0; r < 4; ++r) {
          float v = acc[i][j][r];
          if (z == 1) v = (v > 0.f) ? (v + 1.f) : __expf(v);
          h[r] = bfbits(v);
        }
        uint2 u;
        u.x = (uint32_t)h[0] | ((uint32_t)h[1] << 16);
        u.y = (uint32_t)h[2] | ((uint32_t)h[3] << 16);
        *reinterpret_cast<uint2*>(T + ((size_t)(seq * DIM + d) << 11) + s0) = u;
      }
    }
  }
}

// ksum[seq*512+d] = sum_s KT[seq][d][s]; one wave per row
__global__ __launch_bounds__(256) void ksum_kernel(
    const __bf16* __restrict__ KT, float* __restrict__ ksum)
{
  const int lane = threadIdx.x & 63;
  const int row  = blockIdx.x * 4 + (threadIdx.x >> 6);
  const __bf16* rp = KT + (size_t)row * SLEN;
  float s = 0.f;
#pragma unroll
  for (int k = 0; k < 4; ++k) {
    bf16x8 v = *reinterpret_cast<const bf16x8*>(rp + k * 512 + lane * 8);
#pragma unroll
    for (int t = 0; t < 8; ++t) s += (float)v[t];
  }
#pragma unroll
  for (int off = 32; off > 0; off >>= 1) s += __shfl_xor(s, off, 64);
  if (lane == 0) ksum[row] = s;
}

// den[m] = max(sum_d Q[m,d]*ksum[seq,d], 1e-6); one wave per row
__global__ __launch_bounds__(256) void den_kernel(
    const __bf16* __restrict__ Q, const float* __restrict__ ksum,
    float* __restrict__ den)
{
  const int lane = threadIdx.x & 63;
  const int m = blockIdx.x * 4 + (threadIdx.x >> 6);
  bf16x8 qv = *reinterpret_cast<const bf16x8*>(Q + (size_t)m * DIM + lane * 8);
  const float* kp = ksum + ((m >> 11) << 9) + lane * 8;
  float s = 0.f;
#pragma unroll
  for (int t = 0; t < 8; ++t) s += (float)qv[t] * kp[t];
#pragma unroll
  for (int off = 32; off > 0; off >>= 1) s += __shfl_xor(s, off, 64);
  if (lane == 0) den[m] = fmaxf(s, 1e-6f);
}

// kvT[seq][e][d] = sum_s VT[seq][e][s] * KT[seq][d][s]; grid (4,4,32)
__global__ __launch_bounds__(256) void kv_kernel(
    const __bf16* __restrict__ VT, const __bf16* __restrict__ KT,
    __bf16* __restrict__ kvT)
{
  __shared__ __align__(16) __bf16 Asm[128 * 32];
  __shared__ __align__(16) __bf16 Bsm[128 * 32];
  const int seq = blockIdx.z;
  const __bf16* A = VT + (size_t)seq * DIM * SLEN;
  const __bf16* B = KT + (size_t)seq * DIM * SLEN;
  f32x4 acc[4][4] = {};
  gemm_core(A, SLEN, blockIdx.x * 128, B, SLEN, blockIdx.y * 128, SLEN, Asm, Bsm, acc);

  const int tid = threadIdx.x, wave = tid >> 6, lane = tid & 63;
  const int wr = wave >> 1, wc = wave & 1, lr = lane & 15, kq = lane >> 4;
  const int m0 = blockIdx.x * 128 + wr * 64 + kq * 4;
  const int n0 = blockIdx.y * 128 + wc * 64 + lr;
  __bf16* C = kvT + (size_t)seq * DIM * DIM;
#pragma unroll
  for (int i = 0; i < 4; ++i)
#pragma unroll
    for (int j = 0; j < 4; ++j)
#pragma unroll
      for (int r = 0; r < 4; ++r)
        C[(size_t)(m0 + i * 16 + r) * DIM + (n0 + j * 16)] = (__bf16)acc[i][j][r];
}

// out[m,e] = (sum_d Q[m,d]*kvT[seq][e][d]) / den[m]; grid (512,4)
__global__ __launch_bounds__(256) void num_kernel(
    const __bf16* __restrict__ Q, const __bf16* __restrict__ kvT,
    const float* __restrict__ den, __bf16* __restrict__ out)
{
  __shared__ __align__(16) __bf16 Asm[128 * 32];
  __shared__ __align__(16) __bf16 Bsm[128 * 32];
  const int brow = blockIdx.x, bcol = blockIdx.y;
  const int seq = brow >> 4;
  f32x4 acc[4][4] = {};
  gemm_core(Q, DIM, brow * 128, kvT + (size_t)seq * DIM * DIM, DIM,
            bcol * 128, DIM, Asm, Bsm, acc);

  const int tid = threadIdx.x, wave = tid >> 6, lane = tid & 63;
  const int wr = wave >> 1, wc = wave & 1, lr = lane & 15, kq = lane >> 4;
  const int m0 = brow * 128 + wr * 64 + kq * 4;
  const int n0 = bcol * 128 + wc * 64 + lr;
  float rden[4][4];
#pragma unroll
  for (int i = 0; i < 4; ++i)
#pragma unroll
    for (int r = 0; r < 4; ++r)
      rden[i][r] = 1.f / den[m0 + i * 16 + r];
#pragma unroll
  for (int i = 0; i < 4; ++i)
#pragma unroll
    for (int j = 0; j < 4; ++j)
#pragma unroll
      for (int r = 0; r < 4; ++r)
        out[(size_t)(m0 + i * 16 + r) * DIM + (n0 + j * 16)] =
            (__bf16)(acc[i][j][r] * rden[i][r]);
}

// y[m,o] = sum_e out[m,e]*Wo[o,e] + bo[o] + out[m,o]; y -> d_out (fp32)
__global__ __launch_bounds__(256) void final_kernel(
    const __bf16* __restrict__ outb, const __bf16* __restrict__ Wob,
    const float* __restrict__ bo, float* __restrict__ y)
{
  __shared__ __align__(16) __bf16 Asm[128 * 32];
  __shared__ __align__(16) __bf16 Bsm[128 * 32];
  const int brow = blockIdx.x, bcol = blockIdx.y;
  f32x4 acc[4][4] = {};
  gemm_core(outb, DIM, brow * 128, Wob, DIM, bcol * 128, DIM, Asm, Bsm, acc);

  const int tid = threadIdx.x, wave = tid >> 6, lane = tid & 63;
  const int wr = wave >> 1, wc = wave & 1, lr = lane & 15, kq = lane >> 4;
  const int m0 = brow * 128 + wr * 64 + kq * 4;
  const int n0 = bcol * 128 + wc * 64 + lr;
#pragma unroll
  for (int j = 0; j < 4; ++j) {
    const int n = n0 + j * 16;
    const float bon = bo[n];
#pragma unroll
    for (int i = 0; i < 4; ++i)
#pragma unroll
      for (int r = 0; r < 4; ++r) {
        const int m = m0 + i * 16 + r;
        y[(size_t)m * DIM + n] =
            acc[i][j][r] + bon + (float)outb[(size_t)m * DIM + n];
      }
  }
}

// row LayerNorm over 512, in-place safe; one wave per row
__global__ __launch_bounds__(256) void ln_kernel(
    const float* y, const float* gamma, const float* beta, float* o)
{
  const int lane = threadIdx.x & 63;
  const size_t row = (size_t)blockIdx.x * 4 + (threadIdx.x >> 6);
  const float* yr = y + row * DIM;
  float v[8];
  float s = 0.f, ss = 0.f;
#pragma unroll
  for (int k = 0; k < 8; ++k) {
    v[k] = yr[lane + 64 * k];
    s += v[k];
    ss += v[k] * v[k];
  }
#pragma unroll
  for (int off = 32; off > 0; off >>= 1) {
    s  += __shfl_xor(s, off, 64);
    ss += __shfl_xor(ss, off, 64);
  }
  const float mu  = s * (1.f / 512.f);
  float var = ss * (1.f / 512.f) - mu * mu;
  const float rstd = rsqrtf(var + 1e-5f);
  float* orp = o + row * DIM;
#pragma unroll
  for (int k = 0; k < 8; ++k) {
    const int c = lane + 64 * k;
    orp[c] = (v[k] - mu) * rstd * gamma[c] + beta[c];
  }
}

// ---------- launch ----------
extern "C" void kernel_launch(void* const* d_in, const int* in_sizes, int n_in,
                              void* d_out, int out_size, void* d_ws, size_t ws_size,
                              hipStream_t stream)
{
  const float* x     = (const float*)d_in[0];
  const float* Wq    = (const float*)d_in[1];
  const float* Wk    = (const float*)d_in[2];
  const float* Wv    = (const float*)d_in[3];
  const float* Wo    = (const float*)d_in[4];
  const float* bo    = (const float*)d_in[5];
  const float* gamma = (const float*)d_in[6];
  const float* beta  = (const float*)d_in[7];
  float* outp = (float*)d_out;

  char* ws = (char*)d_ws;
  const size_t SZ = 67108864;                      // 64 Mi (bf16 [65536][512])
  __bf16* xb   = (__bf16*)(ws + 0);                // reused as `out` after QKV
  __bf16* Q    = (__bf16*)(ws + SZ);
  __bf16* KT   = (__bf16*)(ws + 2 * SZ);
  __bf16* VT   = (__bf16*)(ws + 3 * SZ);
  __bf16* kvT  = (__bf16*)(ws + 4 * SZ);           // 16 MiB
  __bf16* Wqb  = (__bf16*)(ws + 4 * SZ + 16777216);
  __bf16* Wkb  = Wqb + 262144;
  __bf16* Wvb  = Wkb + 262144;
  __bf16* Wob  = Wvb + 262144;
  float*  ksum = (float*)(Wob + 262144);           // 64 KiB
  float*  den  = (float*)((char*)ksum + 65536);    // 256 KiB

  cast_kernel<<<4096, 256, 0, stream>>>(x,  xb,  MROWS * DIM / 8);
  cast_kernel<<<128, 256, 0, stream>>>(Wq, Wqb, DIM * DIM / 8);
  cast_kernel<<<128, 256, 0, stream>>>(Wk, Wkb, DIM * DIM / 8);
  cast_kernel<<<128, 256, 0, stream>>>(Wv, Wvb, DIM * DIM / 8);
  cast_kernel<<<128, 256, 0, stream>>>(Wo, Wob, DIM * DIM / 8);

  qkv_kernel<<<dim3(512, 4, 3), 256, 0, stream>>>(xb, Wqb, Wkb, Wvb, Q, KT, VT);
  ksum_kernel<<<4096, 256, 0, stream>>>(KT, ksum);
  den_kernel<<<16384, 256, 0, stream>>>(Q, ksum, den);
  kv_kernel<<<dim3(4, 4, 32), 256, 0, stream>>>(VT, KT, kvT);
  num_kernel<<<dim3(512, 4), 256, 0, stream>>>(Q, kvT, den, xb /*out*/);
  final_kernel<<<dim3(512, 4), 256, 0, stream>>>(xb, Wob, bo, outp /*y*/);
  ln_kernel<<<16384, 256, 0, stream>>>(outp, gamma, beta, outp);
}

// Round 2
// 468.924 us; speedup vs baseline: 1.2106x; 1.2106x over previous
//
#include <hip/hip_runtime.h>
#include <cstdint>

// ---------- types ----------
typedef __bf16 bf16x8 __attribute__((ext_vector_type(8)));
typedef float  f32x4  __attribute__((ext_vector_type(4)));

// Problem constants: BATCH=8, N_SEQS=4, SEQ_LEN=2048, D=512 -> 32 seqs, 65536 rows
#define SEQS   32
#define SLEN   2048
#define DIM    512
#define MROWS  65536

static __device__ __forceinline__ void load_lds16(const void* g, void* l) {
  __builtin_amdgcn_global_load_lds(
      (const __attribute__((address_space(1))) void*)(uintptr_t)g,
      (__attribute__((address_space(3))) void*)(uintptr_t)l,
      16, 0, 0);
}

static __device__ __forceinline__ unsigned short bfbits(float f) {
  __bf16 h = (__bf16)f;
  unsigned short u;
  __builtin_memcpy(&u, &h, 2);
  return u;
}

// ---------- BT-GEMM core, 128x128 tile, BK=64, 256 threads (4 waves 2x2) ----------
// C[m,n] += sum_k A[m,k]*B[n,k]. LDS tiles [128][64] bf16 (128B rows, 8x16B slots),
// XOR-swizzled: LDS byte L holds global col ((slot^(row&7))*8). Writes go through
// global_load_lds with the INVERSE (same) swizzle applied to the global source
// address (linear LDS dest), reads apply the swizzle -> 2-way conflict (free).
static __device__ __forceinline__ void gemm_core(
    const __bf16* __restrict__ A, int lda, int arow0,
    const __bf16* __restrict__ B, int ldb, int brow0,
    int K, __bf16* Asm, __bf16* Bsm, f32x4 (&acc)[4][4])
{
  const int tid  = threadIdx.x;
  const int wave = tid >> 6;
  const int lane = tid & 63;
  const int wr = wave >> 1, wc = wave & 1;
  const int lr = lane & 15, kq = lane >> 4;

  for (int kt = 0; kt < K; kt += 64) {
#pragma unroll
    for (int q = 0; q < 4; ++q) {
      const int L  = q * 4096 + tid * 16;   // linear byte in 16KB region
      const int r  = L >> 7;                // 128B per row
      const int sl = (L >> 4) & 7;          // 16B slot in row
      const int c  = ((sl ^ (r & 7)) << 3); // swizzled element col
      load_lds16(A + (size_t)(arow0 + r) * lda + (kt + c),
                 (char*)Asm + q * 4096 + wave * 1024);
      load_lds16(B + (size_t)(brow0 + r) * ldb + (kt + c),
                 (char*)Bsm + q * 4096 + wave * 1024);
    }
    __syncthreads();

    bf16x8 af[2][4], bfr[2][4];
#pragma unroll
    for (int kk = 0; kk < 2; ++kk)
#pragma unroll
      for (int i = 0; i < 4; ++i) {
        const int rA = wr * 64 + i * 16 + lr;
        af[kk][i] = *reinterpret_cast<const bf16x8*>(
            (char*)Asm + rA * 128 + ((((kk * 4 + kq) ^ (rA & 7))) << 4));
        const int rB = wc * 64 + i * 16 + lr;
        bfr[kk][i] = *reinterpret_cast<const bf16x8*>(
            (char*)Bsm + rB * 128 + ((((kk * 4 + kq) ^ (rB & 7))) << 4));
      }
#pragma unroll
    for (int kk = 0; kk < 2; ++kk)
#pragma unroll
      for (int i = 0; i < 4; ++i)
#pragma unroll
        for (int j = 0; j < 4; ++j)
          acc[i][j] = __builtin_amdgcn_mfma_f32_16x16x32_bf16(
              af[kk][i], bfr[kk][j], acc[i][j], 0, 0, 0);
    __syncthreads();
  }
}

// ---------- kernels ----------

__global__ __launch_bounds__(256) void cast_kernel(
    const float* __restrict__ src, __bf16* __restrict__ dst, int n8)
{
  int i = blockIdx.x * blockDim.x + threadIdx.x;
  const int stride = gridDim.x * blockDim.x;
  for (; i < n8; i += stride) {
    const float4* p = reinterpret_cast<const float4*>(src + (size_t)i * 8);
    float4 a = p[0], b2 = p[1];
    float vals[8] = {a.x, a.y, a.z, a.w, b2.x, b2.y, b2.z, b2.w};
    uint32_t w[4];
#pragma unroll
    for (int t = 0; t < 4; ++t)
      w[t] = (uint32_t)bfbits(vals[2 * t]) | ((uint32_t)bfbits(vals[2 * t + 1]) << 16);
    uint4 o; o.x = w[0]; o.y = w[1]; o.z = w[2]; o.w = w[3];
    *reinterpret_cast<uint4*>(dst + (size_t)i * 8) = o;
  }
}

// 4 weight matrices (512x512 each) in one dispatch, grid (128,4)
__global__ __launch_bounds__(256) void cast4_kernel(
    const float* __restrict__ a, const float* __restrict__ b,
    const float* __restrict__ c, const float* __restrict__ d,
    __bf16* __restrict__ ab, __bf16* __restrict__ bb,
    __bf16* __restrict__ cb, __bf16* __restrict__ db)
{
  const int z = blockIdx.y;
  const float* src = (z == 0) ? a : (z == 1) ? b : (z == 2) ? c : d;
  __bf16* dst = (z == 0) ? ab : (z == 1) ? bb : (z == 2) ? cb : db;
  const int i = blockIdx.x * 256 + threadIdx.x;   // < 32768
  const float4* p = reinterpret_cast<const float4*>(src + (size_t)i * 8);
  float4 x = p[0], y = p[1];
  float vals[8] = {x.x, x.y, x.z, x.w, y.x, y.y, y.z, y.w};
  uint32_t w[4];
#pragma unroll
  for (int t = 0; t < 4; ++t)
    w[t] = (uint32_t)bfbits(vals[2 * t]) | ((uint32_t)bfbits(vals[2 * t + 1]) << 16);
  uint4 o; o.x = w[0]; o.y = w[1]; o.z = w[2]; o.w = w[3];
  *reinterpret_cast<uint4*>(dst + (size_t)i * 8) = o;
}

// QKV projection: grid (12, 512); bx = z*4 + bcol (x-tile consumers adjacent).
// z=0 -> Q (phi), z=1 -> K^T (phi) + ksum atomics, z=2 -> V^T
__global__ __launch_bounds__(256) void qkv_kernel(
    const __bf16* __restrict__ xb,
    const __bf16* __restrict__ Wqb, const __bf16* __restrict__ Wkb,
    const __bf16* __restrict__ Wvb,
    __bf16* __restrict__ Q, __bf16* __restrict__ KT, __bf16* __restrict__ VT,
    float* __restrict__ ksum)
{
  __shared__ __align__(16) __bf16 Asm[128 * 64];
  __shared__ __align__(16) __bf16 Bsm[128 * 64];
  const int z = blockIdx.x >> 2, bcol = blockIdx.x & 3, brow = blockIdx.y;
  const __bf16* W = (z == 0) ? Wqb : (z == 1) ? Wkb : Wvb;
  f32x4 acc[4][4] = {};
  gemm_core(xb, DIM, brow * 128, W, DIM, bcol * 128, DIM, Asm, Bsm, acc);

  const int tid = threadIdx.x, wave = tid >> 6, lane = tid & 63;
  const int wr = wave >> 1, wc = wave & 1, lr = lane & 15, kq = lane >> 4;
  const int m0 = brow * 128 + wr * 64 + kq * 4;
  const int n0 = bcol * 128 + wc * 64 + lr;

  if (z == 0) {
#pragma unroll
    for (int i = 0; i < 4; ++i)
#pragma unroll
      for (int j = 0; j < 4; ++j) {
        const int n = n0 + j * 16;
#pragma unroll
        for (int r = 0; r < 4; ++r) {
          const int m = m0 + i * 16 + r;
          float v = acc[i][j][r];
          v = (v > 0.f) ? (v + 1.f) : __expf(v);   // elu(v)+1
          Q[(size_t)m * DIM + n] = (__bf16)v;
        }
      }
  } else {
    __bf16* T = (z == 1) ? KT : VT;
    const int seq = (brow * 128) >> 11;
    float ks[4] = {0.f, 0.f, 0.f, 0.f};
#pragma unroll
    for (int i = 0; i < 4; ++i) {
      const int mb = m0 + i * 16;
      const int s0 = mb & 2047;
#pragma unroll
      for (int j = 0; j < 4; ++j) {
        const int d = n0 + j * 16;
        unsigned short h[4];
#pragma unroll
        for (int r = 0; r < 4; ++r) {
          float v = acc[i][j][r];
          if (z == 1) { v = (v > 0.f) ? (v + 1.f) : __expf(v); ks[j] += v; }
          h[r] = bfbits(v);
        }
        uint2 u;
        u.x = (uint32_t)h[0] | ((uint32_t)h[1] << 16);
        u.y = (uint32_t)h[2] | ((uint32_t)h[3] << 16);
        *reinterpret_cast<uint2*>(T + ((size_t)(seq * DIM + d) << 11) + s0) = u;
      }
    }
    if (z == 1) {
#pragma unroll
      for (int j = 0; j < 4; ++j) {
        float p = ks[j];
        p += __shfl_xor(p, 16, 64);
        p += __shfl_xor(p, 32, 64);
        if (kq == 0) atomicAdd(&ksum[seq * DIM + n0 + j * 16], p);
      }
    }
  }
}

// den[m] = max(sum_d Q[m,d]*ksum[seq,d], 1e-6); one wave per row
__global__ __launch_bounds__(256) void den_kernel(
    const __bf16* __restrict__ Q, const float* __restrict__ ksum,
    float* __restrict__ den)
{
  const int lane = threadIdx.x & 63;
  const int m = blockIdx.x * 4 + (threadIdx.x >> 6);
  bf16x8 qv = *reinterpret_cast<const bf16x8*>(Q + (size_t)m * DIM + lane * 8);
  const float* kp = ksum + ((m >> 11) << 9) + lane * 8;
  float s = 0.f;
#pragma unroll
  for (int t = 0; t < 8; ++t) s += (float)qv[t] * kp[t];
#pragma unroll
  for (int off = 32; off > 0; off >>= 1) s += __shfl_xor(s, off, 64);
  if (lane == 0) den[m] = fmaxf(s, 1e-6f);
}

// kvT[seq][e][d] = sum_s VT[seq][e][s] * KT[seq][d][s]; grid (4,4,32)
__global__ __launch_bounds__(256) void kv_kernel(
    const __bf16* __restrict__ VT, const __bf16* __restrict__ KT,
    __bf16* __restrict__ kvT)
{
  __shared__ __align__(16) __bf16 Asm[128 * 64];
  __shared__ __align__(16) __bf16 Bsm[128 * 64];
  const int seq = blockIdx.z;
  const __bf16* A = VT + (size_t)seq * DIM * SLEN;
  const __bf16* B = KT + (size_t)seq * DIM * SLEN;
  f32x4 acc[4][4] = {};
  gemm_core(A, SLEN, blockIdx.x * 128, B, SLEN, blockIdx.y * 128, SLEN, Asm, Bsm, acc);

  const int tid = threadIdx.x, wave = tid >> 6, lane = tid & 63;
  const int wr = wave >> 1, wc = wave & 1, lr = lane & 15, kq = lane >> 4;
  const int m0 = blockIdx.x * 128 + wr * 64 + kq * 4;
  const int n0 = blockIdx.y * 128 + wc * 64 + lr;
  __bf16* C = kvT + (size_t)seq * DIM * DIM;
#pragma unroll
  for (int i = 0; i < 4; ++i)
#pragma unroll
    for (int j = 0; j < 4; ++j)
#pragma unroll
      for (int r = 0; r < 4; ++r)
        C[(size_t)(m0 + i * 16 + r) * DIM + (n0 + j * 16)] = (__bf16)acc[i][j][r];
}

// out[m,e] = (sum_d Q[m,d]*kvT[seq][e][d]) / den[m]; grid (4,512) bx=bcol
__global__ __launch_bounds__(256) void num_kernel(
    const __bf16* __restrict__ Q, const __bf16* __restrict__ kvT,
    const float* __restrict__ den, __bf16* __restrict__ out)
{
  __shared__ __align__(16) __bf16 Asm[128 * 64];
  __shared__ __align__(16) __bf16 Bsm[128 * 64];
  const int bcol = blockIdx.x, brow = blockIdx.y;
  const int seq = brow >> 4;
  f32x4 acc[4][4] = {};
  gemm_core(Q, DIM, brow * 128, kvT + (size_t)seq * DIM * DIM, DIM,
            bcol * 128, DIM, Asm, Bsm, acc);

  const int tid = threadIdx.x, wave = tid >> 6, lane = tid & 63;
  const int wr = wave >> 1, wc = wave & 1, lr = lane & 15, kq = lane >> 4;
  const int m0 = brow * 128 + wr * 64 + kq * 4;
  const int n0 = bcol * 128 + wc * 64 + lr;
  float rden[4][4];
#pragma unroll
  for (int i = 0; i < 4; ++i)
#pragma unroll
    for (int r = 0; r < 4; ++r)
      rden[i][r] = 1.f / den[m0 + i * 16 + r];
#pragma unroll
  for (int i = 0; i < 4; ++i)
#pragma unroll
    for (int j = 0; j < 4; ++j)
#pragma unroll
      for (int r = 0; r < 4; ++r)
        out[(size_t)(m0 + i * 16 + r) * DIM + (n0 + j * 16)] =
            (__bf16)(acc[i][j][r] * rden[i][r]);
}

// Fused out-proj + bias + residual + LayerNorm. One block = 128 rows x full 512
// cols, 512 threads (8 waves, 4x2). Tile: A=out[128x512] (K=e), B=Wo[512x512].
// LDS: Asm 8KB [128][32] + Bsm 32KB [512][32], BK=32, same XOR swizzle (row&3).
__global__ __launch_bounds__(512) void final_kernel(
    const __bf16* __restrict__ outb, const __bf16* __restrict__ Wob,
    const float* __restrict__ bo, const float* __restrict__ gamma,
    const float* __restrict__ beta, float* __restrict__ y)
{
  __shared__ __align__(16) __bf16 Asm[128 * 32];
  __shared__ __align__(16) __bf16 Bsm[512 * 32];
  __shared__ float redS[2][128], redSS[2][128];
  const int tid = threadIdx.x, wave = tid >> 6, lane = tid & 63;
  const int wr = wave >> 2, wc = wave & 3;   // placeholder, fixed below
  (void)wr; (void)wc;
  const int Wr = wave >> 1, Wc = wave & 1;   // 4x2 wave grid: 32 rows x 256 cols each
  const int lr = lane & 15, kq = lane >> 4;
  const int brow = blockIdx.x;
  f32x4 acc[2][16] = {};

  for (int kt = 0; kt < DIM; kt += 32) {
    {
      const int L = tid * 16;               // 8KB A region
      const int r = L >> 6, sl = (L >> 4) & 3;
      const int c = ((sl ^ (r & 3)) << 3);
      load_lds16(outb + (size_t)(brow * 128 + r) * DIM + (kt + c),
                 (char*)Asm + wave * 1024);
#pragma unroll
      for (int q = 0; q < 4; ++q) {         // 32KB B region
        const int Lb = q * 8192 + tid * 16;
        const int rb = Lb >> 6, slb = (Lb >> 4) & 3;
        const int cb = ((slb ^ (rb & 3)) << 3);
        load_lds16(Wob + (size_t)rb * DIM + (kt + cb),
                   (char*)Bsm + q * 8192 + wave * 1024);
      }
    }
    __syncthreads();
    bf16x8 af[2];
#pragma unroll
    for (int i = 0; i < 2; ++i) {
      const int rA = Wr * 32 + i * 16 + lr;
      af[i] = *reinterpret_cast<const bf16x8*>(
          (char*)Asm + rA * 64 + ((kq ^ (rA & 3)) << 4));
    }
#pragma unroll
    for (int j = 0; j < 16; ++j) {
      const int rB = Wc * 256 + j * 16 + lr;
      bf16x8 bf = *reinterpret_cast<const bf16x8*>(
          (char*)Bsm + rB * 64 + ((kq ^ (rB & 3)) << 4));
#pragma unroll
      for (int i = 0; i < 2; ++i)
        acc[i][j] = __builtin_amdgcn_mfma_f32_16x16x32_bf16(af[i], bf, acc[i][j], 0, 0, 0);
    }
    __syncthreads();
  }

  // epilogue: y = acc + bo + residual; LN over the 512 cols of each row
  const int m0g = brow * 128;
  float sA[2][4], ssA[2][4];
#pragma unroll
  for (int i = 0; i < 2; ++i)
#pragma unroll
    for (int r = 0; r < 4; ++r) { sA[i][r] = 0.f; ssA[i][r] = 0.f; }
#pragma unroll
  for (int j = 0; j < 16; ++j) {
    const int n = Wc * 256 + j * 16 + lr;
    const float bon = bo[n];
#pragma unroll
    for (int i = 0; i < 2; ++i) {
      const int mb = m0g + Wr * 32 + i * 16 + kq * 4;
#pragma unroll
      for (int r = 0; r < 4; ++r) {
        float v = acc[i][j][r] + bon + (float)outb[(size_t)(mb + r) * DIM + n];
        acc[i][j][r] = v;
        sA[i][r] += v; ssA[i][r] += v * v;
      }
    }
  }
#pragma unroll
  for (int i = 0; i < 2; ++i)
#pragma unroll
    for (int r = 0; r < 4; ++r) {
      float s = sA[i][r], ss = ssA[i][r];
#pragma unroll
      for (int off = 1; off <= 8; off <<= 1) {
        s  += __shfl_xor(s,  off, 64);
        ss += __shfl_xor(ss, off, 64);
      }
      if (lr == 0) {
        const int ml = Wr * 32 + i * 16 + kq * 4 + r;
        redS[Wc][ml] = s; redSS[Wc][ml] = ss;
      }
    }
  __syncthreads();
  float mu_[2][4], rs_[2][4];
#pragma unroll
  for (int i = 0; i < 2; ++i)
#pragma unroll
    for (int r = 0; r < 4; ++r) {
      const int ml = Wr * 32 + i * 16 + kq * 4 + r;
      const float S  = redS[0][ml]  + redS[1][ml];
      const float SS = redSS[0][ml] + redSS[1][ml];
      const float mu = S * (1.f / 512.f);
      const float var = SS * (1.f / 512.f) - mu * mu;
      mu_[i][r] = mu;
      rs_[i][r] = rsqrtf(var + 1e-5f);
    }
#pragma unroll
  for (int j = 0; j < 16; ++j) {
    const int n = Wc * 256 + j * 16 + lr;
    const float g = gamma[n], b = beta[n];
#pragma unroll
    for (int i = 0; i < 2; ++i) {
      const int mb = m0g + Wr * 32 + i * 16 + kq * 4;
#pragma unroll
      for (int r = 0; r < 4; ++r)
        y[(size_t)(mb + r) * DIM + n] = (acc[i][j][r] - mu_[i][r]) * rs_[i][r] * g + b;
    }
  }
}

// ---------- launch ----------
extern "C" void kernel_launch(void* const* d_in, const int* in_sizes, int n_in,
                              void* d_out, int out_size, void* d_ws, size_t ws_size,
                              hipStream_t stream)
{
  const float* x     = (const float*)d_in[0];
  const float* Wq    = (const float*)d_in[1];
  const float* Wk    = (const float*)d_in[2];
  const float* Wv    = (const float*)d_in[3];
  const float* Wo    = (const float*)d_in[4];
  const float* bo    = (const float*)d_in[5];
  const float* gamma = (const float*)d_in[6];
  const float* beta  = (const float*)d_in[7];
  float* outp = (float*)d_out;

  char* ws = (char*)d_ws;
  const size_t SZ = 67108864;                      // 64 MiB (bf16 [65536][512])
  __bf16* xb   = (__bf16*)(ws + 0);                // reused as `out` after qkv
  __bf16* Q    = (__bf16*)(ws + SZ);
  __bf16* KT   = (__bf16*)(ws + 2 * SZ);
  __bf16* VT   = (__bf16*)(ws + 3 * SZ);
  __bf16* kvT  = (__bf16*)(ws + 4 * SZ);           // 16 MiB
  __bf16* Wqb  = (__bf16*)(ws + 4 * SZ + 16777216);
  __bf16* Wkb  = Wqb + 262144;
  __bf16* Wvb  = Wkb + 262144;
  __bf16* Wob  = Wvb + 262144;
  float*  ksum = (float*)(Wob + 262144);           // 32*512 f32 = 64 KiB
  float*  den  = (float*)((char*)ksum + 65536);    // 256 KiB

  hipMemsetAsync(ksum, 0, SEQS * DIM * sizeof(float), stream);
  cast_kernel<<<4096, 256, 0, stream>>>(x, xb, MROWS * DIM / 8);
  cast4_kernel<<<dim3(128, 4), 256, 0, stream>>>(Wq, Wk, Wv, Wo, Wqb, Wkb, Wvb, Wob);

  qkv_kernel<<<dim3(12, 512), 256, 0, stream>>>(xb, Wqb, Wkb, Wvb, Q, KT, VT, ksum);
  den_kernel<<<16384, 256, 0, stream>>>(Q, ksum, den);
  kv_kernel<<<dim3(4, 4, 32), 256, 0, stream>>>(VT, KT, kvT);
  num_kernel<<<dim3(4, 512), 256, 0, stream>>>(Q, kvT, den, xb /*out*/);
  final_kernel<<<512, 512, 0, stream>>>(xb, Wob, bo, gamma, beta, outp);
}